// Round 3
// baseline (223.292 us; speedup 1.0000x reference)
//
#include <hip/hip_runtime.h>

// Problem constants (match reference)
#define N_PTS 1048576
#define C_PT 9
#define C_LB 20
#define V1 500000
#define V8 65536

// Bucketing: 256 bins per bucket
#define NB1 1954                 // ceil(V1/256)
#define NB8 256                  // V8/256
#define NBT (NB1 + NB8)          // 2210
#define KBLOCKS 256
#define PTS_PER_BLOCK (N_PTS / KBLOCKS)   // 4096
#define LB_STRIDE 21             // gcd(21,32)=1 -> conflict-free-ish LDS rows

// K1: per-block LDS histogram over all 2210 buckets -> u16 matrix row.
__global__ __launch_bounds__(1024) void count_kernel(const int* __restrict__ inv1,
                                                     const int* __restrict__ inv8,
                                                     unsigned short* __restrict__ mat)
{
    __shared__ int hist[NBT];
    for (int k = threadIdx.x; k < NBT; k += 1024) hist[k] = 0;
    __syncthreads();
    int base_i = blockIdx.x * PTS_PER_BLOCK;
    for (int t = threadIdx.x; t < PTS_PER_BLOCK; t += 1024) {
        int i = base_i + t;
        atomicAdd(&hist[inv1[i] >> 8], 1);
        atomicAdd(&hist[NB1 + (inv8[i] >> 8)], 1);
    }
    __syncthreads();
    unsigned short* row = mat + (size_t)blockIdx.x * NBT;
    for (int k = threadIdx.x; k < NBT; k += 1024) row[k] = (unsigned short)hist[k];
}

// S1: per-bucket (column) exclusive scan over the 256 blocks, in place.
// One wave per bucket. Also emits per-bucket totals.
__global__ __launch_bounds__(256) void colscan_kernel(unsigned short* __restrict__ mat,
                                                      int* __restrict__ total)
{
    int wave = (int)((blockIdx.x * 256 + threadIdx.x) >> 6);
    int lane = threadIdx.x & 63;
    if (wave >= NBT) return;
    int carry = 0;
    for (int c = 0; c < KBLOCKS; c += 64) {
        int b = c + lane;
        int v = (int)mat[(size_t)b * NBT + wave];
        int s = v;
        #pragma unroll
        for (int d = 1; d < 64; d <<= 1) {
            int u = __shfl_up(s, d, 64);
            if (lane >= d) s += u;
        }
        mat[(size_t)b * NBT + wave] = (unsigned short)(s - v + carry);
        carry += __shfl(s, 63, 64);
    }
    if (lane == 0) total[wave] = carry;
}

// S2: exclusive scan of bucket totals -> base. Separate scans for the two
// scales (sorted1 and sorted8 are separate arrays, both start at 0).
__global__ __launch_bounds__(64) void basescan_kernel(const int* __restrict__ total,
                                                      int* __restrict__ base)
{
    int lane = threadIdx.x;
    int carry = 0;
    for (int c = 0; c < NB1; c += 64) {
        int k = c + lane;
        int v = (k < NB1) ? total[k] : 0;
        int s = v;
        #pragma unroll
        for (int d = 1; d < 64; d <<= 1) {
            int u = __shfl_up(s, d, 64);
            if (lane >= d) s += u;
        }
        if (k < NB1) base[k] = s - v + carry;
        carry += __shfl(s, 63, 64);
    }
    carry = 0;
    for (int c = 0; c < NB8; c += 64) {
        int k = c + lane;
        int v = total[NB1 + k];
        int s = v;
        #pragma unroll
        for (int d = 1; d < 64; d <<= 1) {
            int u = __shfl_up(s, d, 64);
            if (lane >= d) s += u;
        }
        base[NB1 + k] = s - v + carry;
        carry += __shfl(s, 63, 64);
    }
}

// K2: place each point id (packed with its 8-bit in-bucket bin) into the
// sorted arrays. Rank via LDS atomics only; order within a bucket is
// irrelevant (float accumulation, loose threshold).
__global__ __launch_bounds__(1024) void scatter_kernel(const int* __restrict__ inv1,
                                                       const int* __restrict__ inv8,
                                                       const unsigned short* __restrict__ mat,
                                                       const int* __restrict__ base,
                                                       int* __restrict__ sorted1,
                                                       int* __restrict__ sorted8)
{
    __shared__ int off[NBT];
    __shared__ int cnt[NBT];
    const unsigned short* row = mat + (size_t)blockIdx.x * NBT;
    for (int k = threadIdx.x; k < NBT; k += 1024) {
        off[k] = base[k] + (int)row[k];
        cnt[k] = 0;
    }
    __syncthreads();
    int base_i = blockIdx.x * PTS_PER_BLOCK;
    for (int t = threadIdx.x; t < PTS_PER_BLOCK; t += 1024) {
        int i = base_i + t;
        int v1 = inv1[i];
        int k1 = v1 >> 8;
        int r1 = atomicAdd(&cnt[k1], 1);
        sorted1[off[k1] + r1] = i | ((v1 & 255) << 20);
        int v8 = inv8[i];
        int k8 = NB1 + (v8 >> 8);
        int r8 = atomicAdd(&cnt[k8], 1);
        sorted8[off[k8] + r8] = i | ((v8 & 255) << 20);
    }
}

// K3: labels accumulation. One block per scale-8 bucket: 256 bins x 20ch in
// LDS (stride 21 to spread banks), gather rows, write output once.
__global__ __launch_bounds__(1024) void accum8_kernel(const float* __restrict__ labels,
                                                      const int* __restrict__ sorted8,
                                                      const int* __restrict__ base,
                                                      const int* __restrict__ total,
                                                      float* __restrict__ lbl_out)
{
    __shared__ float acc[256 * LB_STRIDE];
    __shared__ int cnt[256];
    for (int j = threadIdx.x; j < 256 * LB_STRIDE; j += 1024) acc[j] = 0.0f;
    if (threadIdx.x < 256) cnt[threadIdx.x] = 0;
    __syncthreads();
    int b = blockIdx.x;
    int start = base[NB1 + b];
    int num   = total[NB1 + b];
    for (int t = threadIdx.x; t < num; t += 1024) {
        int packed = sorted8[start + t];
        int idx = packed & 0xFFFFF;
        int bin = packed >> 20;
        const float* __restrict__ l = labels + (size_t)idx * C_LB;
        float* a = acc + bin * LB_STRIDE;
        #pragma unroll
        for (int c = 0; c < C_LB; ++c) atomicAdd(&a[c], l[c]);
        atomicAdd(&cnt[bin], 1);
    }
    __syncthreads();
    size_t obase = (size_t)b * 256 * C_LB;
    for (int j = threadIdx.x; j < 256 * C_LB; j += 1024) {
        int bin = j / C_LB, c = j - bin * C_LB;
        int n = cnt[bin];
        float d = (float)(n > 0 ? n : 1);
        lbl_out[obase + (size_t)bin * C_LB + c] = acc[bin * LB_STRIDE + c] / d;
    }
}

// K4: point-features accumulation. One block per scale-1 bucket (last bucket
// partial: 32 bins). Stride 9 already coprime with 32 banks.
__global__ __launch_bounds__(256) void accum1_kernel(const float* __restrict__ points,
                                                     const int* __restrict__ sorted1,
                                                     const int* __restrict__ base,
                                                     const int* __restrict__ total,
                                                     float* __restrict__ feat_out)
{
    __shared__ float acc[256 * C_PT];
    __shared__ int cnt[256];
    for (int j = threadIdx.x; j < 256 * C_PT; j += 256) acc[j] = 0.0f;
    cnt[threadIdx.x] = 0;
    __syncthreads();
    int b = blockIdx.x;
    int start = base[b];
    int num   = total[b];
    for (int t = threadIdx.x; t < num; t += 256) {
        int packed = sorted1[start + t];
        int idx = packed & 0xFFFFF;
        int bin = packed >> 20;
        const float* __restrict__ p = points + (size_t)idx * C_PT;
        float* a = acc + bin * C_PT;
        #pragma unroll
        for (int c = 0; c < C_PT; ++c) atomicAdd(&a[c], p[c]);
        atomicAdd(&cnt[bin], 1);
    }
    __syncthreads();
    int vbase = b * 256;
    int nbins = min(256, V1 - vbase);
    for (int j = threadIdx.x; j < nbins * C_PT; j += 256) {
        int bin = j / C_PT, c = j - bin * C_PT;
        int n = cnt[bin];
        float d = (float)(n > 0 ? n : 1);
        feat_out[(size_t)(vbase + bin) * C_PT + c] = acc[bin * C_PT + c] / d;
    }
}

// ---------------- Fallback (R0 atomic scatter) — only if ws too small ------
__global__ void voxel_scatter_add_kernel(const float* __restrict__ points,
                                         const int* __restrict__ inv1,
                                         const float* __restrict__ labels,
                                         const int* __restrict__ inv8,
                                         float* feat_sum, float* lbl_sum,
                                         float* cnt1, float* cnt8)
{
    int i = blockIdx.x * blockDim.x + threadIdx.x;
    if (i >= N_PTS) return;
    int v1 = inv1[i];
    int v8 = inv8[i];
    const float* p = points + (size_t)i * C_PT;
    float* f = feat_sum + (size_t)v1 * C_PT;
#pragma unroll
    for (int c = 0; c < C_PT; ++c) atomicAdd(&f[c], p[c]);
    atomicAdd(&cnt1[v1], 1.0f);
    const float* l = labels + (size_t)i * C_LB;
    float* o = lbl_sum + (size_t)v8 * C_LB;
#pragma unroll
    for (int c = 0; c < C_LB; ++c) atomicAdd(&o[c], l[c]);
    atomicAdd(&cnt8[v8], 1.0f);
}

__global__ void voxel_divide_kernel(float* out, const float* cnt1, const float* cnt8)
{
    const int totaln = V1 * C_PT + V8 * C_LB;
    for (int i = blockIdx.x * blockDim.x + threadIdx.x; i < totaln;
         i += gridDim.x * blockDim.x) {
        float c = (i < V1 * C_PT) ? cnt1[i / C_PT] : cnt8[(i - V1 * C_PT) / C_LB];
        out[i] /= fmaxf(c, 1.0f);
    }
}

extern "C" void kernel_launch(void* const* d_in, const int* in_sizes, int n_in,
                              void* d_out, int out_size, void* d_ws, size_t ws_size,
                              hipStream_t stream) {
    const float* points = (const float*)d_in[0];
    const int*   inv1   = (const int*)d_in[1];
    const float* labels = (const float*)d_in[2];
    const int*   inv8   = (const int*)d_in[3];

    float* out      = (float*)d_out;
    float* feat_out = out;                       // [V1, C_PT]
    float* lbl_out  = out + (size_t)V1 * C_PT;   // [V8, C_LB]

    // ws layout: sorted1[N] | sorted8[N] | total[NBT] | base[NBT] | mat u16[256][NBT]
    const size_t need = ((size_t)2 * N_PTS + 2 * NBT) * sizeof(int)
                      + (size_t)KBLOCKS * NBT * sizeof(unsigned short);
    if (ws_size >= need) {
        int* sorted1 = (int*)d_ws;
        int* sorted8 = sorted1 + N_PTS;
        int* total   = sorted8 + N_PTS;
        int* basep   = total + NBT;
        unsigned short* mat = (unsigned short*)(basep + NBT);

        count_kernel<<<KBLOCKS, 1024, 0, stream>>>(inv1, inv8, mat);
        colscan_kernel<<<(NBT + 3) / 4, 256, 0, stream>>>(mat, total);
        basescan_kernel<<<1, 64, 0, stream>>>(total, basep);
        scatter_kernel<<<KBLOCKS, 1024, 0, stream>>>(inv1, inv8, mat, basep,
                                                     sorted1, sorted8);
        accum8_kernel<<<NB8, 1024, 0, stream>>>(labels, sorted8, basep, total, lbl_out);
        accum1_kernel<<<NB1, 256, 0, stream>>>(points, sorted1, basep, total, feat_out);
    } else {
        // Fallback: naive atomic scatter (correct, slower).
        float* cnt1 = (float*)d_ws;
        float* cnt8 = cnt1 + V1;
        hipMemsetAsync(d_out, 0, (size_t)out_size * sizeof(float), stream);
        hipMemsetAsync(d_ws, 0, ((size_t)V1 + V8) * sizeof(float), stream);
        const int block = 256;
        voxel_scatter_add_kernel<<<(N_PTS + block - 1) / block, block, 0, stream>>>(
            points, inv1, labels, inv8, feat_out, lbl_out, cnt1, cnt8);
        voxel_divide_kernel<<<2048, block, 0, stream>>>(out, cnt1, cnt8);
    }
}